// Round 1
// baseline (564.187 us; speedup 1.0000x reference)
//
#include <hip/hip_runtime.h>
#include <hip/hip_bf16.h>

// ---------------- problem constants (hardcoded from setup_inputs) ----------
// B=2, T=2, C=256, heads=8, levels=4, points=4, head_dim=32
// level shapes: (64,64),(32,32),(16,16),(8,8); Bt=4
// rows per level (Bt*HW): 16384, 4096, 1024, 256 ; total NR=21760
#define NR 21760

__device__ __forceinline__ int level_of_row(int R) {
    // bases: 0, 16384, 20480, 21504
    if (R < 16384) return 0;
    if (R < 20480) return 1;
    if (R < 21504) return 2;
    return 3;
}

// ---------------- K1: pack [B,C,H,W,T] -> XP[row][c], row=(l,bt,p) ---------
__global__ __launch_bounds__(256) void pack_kernel(const float* __restrict__ f,
                                                   float* __restrict__ XP,
                                                   int Hl, int Wl, int rowbase) {
    const int HW = Hl * Wl;
    const int HWT = HW * 2;
    const int j0 = blockIdx.x * 64;
    const int c0 = blockIdx.y * 64;
    const int b  = blockIdx.z;
    __shared__ float tile[64][65];
    {
        const int tj = threadIdx.x & 63;
        const int tcb = threadIdx.x >> 6;
        const float* fb = f + (size_t)(b * 256 + c0) * HWT + j0;
#pragma unroll
        for (int i = 0; i < 16; ++i) {
            int cl = tcb + i * 4;
            tile[cl][tj] = fb[(size_t)cl * HWT + tj];
        }
    }
    __syncthreads();
    {
        const int tc = threadIdx.x & 63;
        const int tjb = threadIdx.x >> 6;
#pragma unroll
        for (int i = 0; i < 16; ++i) {
            int jl = tjb + i * 4;
            int j = j0 + jl;
            int p = j >> 1, t = j & 1;
            int row = rowbase + (b * 2 + t) * HW + p;
            XP[(size_t)row * 256 + c0 + tc] = tile[tc][jl];
        }
    }
}

// ---------------- K2: generic fp32 GEMM  C[M,N] = A[M,K]@B[K,N] + bias -----
__global__ __launch_bounds__(256) void gemm_kernel(const float* __restrict__ A,
                                                   const float* __restrict__ Bm,
                                                   const float* __restrict__ bias,
                                                   float* __restrict__ C,
                                                   int M, int N, int K) {
    __shared__ float As[16][65];
    __shared__ float Bs[16][65];
    const int row0 = blockIdx.x * 64;
    const int col0 = blockIdx.y * 64;
    const int tm = threadIdx.x >> 4;
    const int tn = threadIdx.x & 15;
    const int la_k = threadIdx.x & 15;
    const int la_m = threadIdx.x >> 4;   // 0..15
    const int lb_n = threadIdx.x & 63;
    const int lb_k = threadIdx.x >> 6;   // 0..3
    float acc[4][4] = {};

    for (int kt = 0; kt < K; kt += 16) {
#pragma unroll
        for (int i = 0; i < 4; ++i) {
            int m = la_m + 16 * i;
            As[la_k][m] = A[(size_t)(row0 + m) * K + kt + la_k];
        }
#pragma unroll
        for (int i = 0; i < 4; ++i) {
            int k = lb_k + 4 * i;
            Bs[k][lb_n] = Bm[(size_t)(kt + k) * N + col0 + lb_n];
        }
        __syncthreads();
#pragma unroll
        for (int kk = 0; kk < 16; ++kk) {
            float a[4], b[4];
#pragma unroll
            for (int i = 0; i < 4; ++i) a[i] = As[kk][tm * 4 + i];
#pragma unroll
            for (int j = 0; j < 4; ++j) b[j] = Bs[kk][tn * 4 + j];
#pragma unroll
            for (int i = 0; i < 4; ++i)
#pragma unroll
                for (int j = 0; j < 4; ++j) acc[i][j] += a[i] * b[j];
        }
        __syncthreads();
    }
#pragma unroll
    for (int j = 0; j < 4; ++j) {
        float bb = bias[col0 + tn * 4 + j];
#pragma unroll
        for (int i = 0; i < 4; ++i)
            C[(size_t)(row0 + tm * 4 + i) * N + col0 + tn * 4 + j] = acc[i][j] + bb;
    }
}

// ---------------- K6: out-proj GEMM with scatter epilogue ------------------
__global__ __launch_bounds__(256) void gemm_scatter_kernel(const float* __restrict__ A,
                                                           const float* __restrict__ Bm,
                                                           const float* __restrict__ bias,
                                                           float* __restrict__ out,
                                                           int M, int K) {
    const int N = 256;
    __shared__ float As[16][65];
    __shared__ float Bs[16][65];
    const int row0 = blockIdx.x * 64;
    const int col0 = blockIdx.y * 64;
    const int tm = threadIdx.x >> 4;
    const int tn = threadIdx.x & 15;
    const int la_k = threadIdx.x & 15;
    const int la_m = threadIdx.x >> 4;
    const int lb_n = threadIdx.x & 63;
    const int lb_k = threadIdx.x >> 6;
    float acc[4][4] = {};

    for (int kt = 0; kt < K; kt += 16) {
#pragma unroll
        for (int i = 0; i < 4; ++i) {
            int m = la_m + 16 * i;
            As[la_k][m] = A[(size_t)(row0 + m) * K + kt + la_k];
        }
#pragma unroll
        for (int i = 0; i < 4; ++i) {
            int k = lb_k + 4 * i;
            Bs[k][lb_n] = Bm[(size_t)(kt + k) * N + col0 + lb_n];
        }
        __syncthreads();
#pragma unroll
        for (int kk = 0; kk < 16; ++kk) {
            float a[4], b[4];
#pragma unroll
            for (int i = 0; i < 4; ++i) a[i] = As[kk][tm * 4 + i];
#pragma unroll
            for (int j = 0; j < 4; ++j) b[j] = Bs[kk][tn * 4 + j];
#pragma unroll
            for (int i = 0; i < 4; ++i)
#pragma unroll
                for (int j = 0; j < 4; ++j) acc[i][j] += a[i] * b[j];
        }
        __syncthreads();
    }
    // scatter epilogue: row -> (level, bt, p) ; out[b, c, y, x, t] per level
    const int lvl = level_of_row(row0);
    const int qbase[4]   = {0, 16384, 20480, 21504};
    const int wtab[4]    = {64, 32, 16, 8};
    const size_t obase[4] = {0, 4194304, 5242880, 5505024};
    const int Wl = wtab[lvl];
    const int HW = Wl * Wl;
#pragma unroll
    for (int i = 0; i < 4; ++i) {
        int R = row0 + tm * 4 + i;
        int r2 = R - qbase[lvl];
        int bt = r2 / HW;
        int p  = r2 - bt * HW;
        int b  = bt >> 1, t = bt & 1;
        int y  = p / Wl, x = p - y * Wl;
#pragma unroll
        for (int j = 0; j < 4; ++j) {
            int c = col0 + tn * 4 + j;
            size_t addr = obase[lvl] + ((((size_t)b * 256 + c) * Wl + y) * Wl + x) * 2 + t;
            out[addr] = acc[i][j] + bias[c];
        }
    }
}

// ---------------- K4: softmax over 16 (L*K) per (row, head) ----------------
__global__ __launch_bounds__(256) void softmax_kernel(float* __restrict__ ATT) {
    int g = blockIdx.x * 256 + threadIdx.x;
    if (g >= NR * 8) return;
    float* p = ATT + (size_t)(g >> 3) * 128 + (g & 7) * 16;
    float v[16];
    float4* p4 = (float4*)p;
#pragma unroll
    for (int i = 0; i < 4; ++i) {
        float4 t = p4[i];
        v[i * 4 + 0] = t.x; v[i * 4 + 1] = t.y; v[i * 4 + 2] = t.z; v[i * 4 + 3] = t.w;
    }
    float m = v[0];
#pragma unroll
    for (int i = 1; i < 16; ++i) m = fmaxf(m, v[i]);
    float s = 0.f;
#pragma unroll
    for (int i = 0; i < 16; ++i) { v[i] = expf(v[i] - m); s += v[i]; }
    float r = 1.0f / s;
#pragma unroll
    for (int i = 0; i < 4; ++i) {
        float4 t;
        t.x = v[i * 4 + 0] * r; t.y = v[i * 4 + 1] * r; t.z = v[i * 4 + 2] * r; t.w = v[i * 4 + 3] * r;
        p4[i] = t;
    }
}

// ---------------- K5: deformable sampling + weighted sum -------------------
__global__ __launch_bounds__(256) void sample_kernel(const float* __restrict__ VAL,
                                                     const float* __restrict__ OFF,
                                                     const float* __restrict__ AW,
                                                     float* __restrict__ SAMP) {
    const int h = threadIdx.x >> 5;
    const int d = threadIdx.x & 31;
    const int qbase[4] = {0, 16384, 20480, 21504};
    const int wtab[4]  = {64, 32, 16, 8};

    for (int qi = 0; qi < 8; ++qi) {
        int R = blockIdx.x * 8 + qi;
        int lq = level_of_row(R);
        int Wq = wtab[lq];
        int HWq = Wq * Wq;
        int r2 = R - qbase[lq];
        int bt = r2 / HWq;
        int p  = r2 - bt * HWq;
        float refx = ((p % Wq) + 0.5f) / (float)Wq;
        float refy = ((p / Wq) + 0.5f) / (float)Wq;

        const float* offrow = OFF + (size_t)R * 256 + h * 32;
        const float* awrow  = AW  + (size_t)R * 128 + h * 16;
        float acc = 0.f;
#pragma unroll
        for (int l = 0; l < 4; ++l) {
            const int Wl = wtab[l];
            const int HWl = Wl * Wl;
            const float* vb = VAL + ((size_t)qbase[l] + (size_t)bt * HWl) * 256 + h * 32 + d;
            const float invW = 1.0f / (float)Wl;
#pragma unroll
            for (int k = 0; k < 4; ++k) {
                float ox = offrow[(l * 4 + k) * 2 + 0];
                float oy = offrow[(l * 4 + k) * 2 + 1];
                float w  = awrow[l * 4 + k];
                float lx = fminf(fmaxf(refx + ox * invW, 0.f), 1.f);
                float ly = fminf(fmaxf(refy + oy * invW, 0.f), 1.f);
                float px = lx * Wl - 0.5f;
                float py = ly * Wl - 0.5f;
                float x0f = floorf(px), y0f = floorf(py);
                int x0 = (int)x0f, y0 = (int)y0f;
                float wx = px - x0f, wy = py - y0f;
                bool xv0 = (x0 >= 0) && (x0 < Wl);
                bool xv1 = (x0 + 1 >= 0) && (x0 + 1 < Wl);
                bool yv0 = (y0 >= 0) && (y0 < Wl);
                bool yv1 = (y0 + 1 >= 0) && (y0 + 1 < Wl);
                float v00 = 0.f, v10 = 0.f, v01 = 0.f, v11 = 0.f;
                if (yv0) {
                    if (xv0) v00 = vb[(size_t)(y0 * Wl + x0) * 256];
                    if (xv1) v10 = vb[(size_t)(y0 * Wl + x0 + 1) * 256];
                }
                if (yv1) {
                    if (xv0) v01 = vb[(size_t)((y0 + 1) * Wl + x0) * 256];
                    if (xv1) v11 = vb[(size_t)((y0 + 1) * Wl + x0 + 1) * 256];
                }
                acc += w * ((1.f - wx) * (1.f - wy) * v00 + wx * (1.f - wy) * v10 +
                            (1.f - wx) * wy * v01 + wx * wy * v11);
            }
        }
        SAMP[(size_t)R * 256 + h * 32 + d] = acc;
    }
}

// ---------------- launch ---------------------------------------------------
extern "C" void kernel_launch(void* const* d_in, const int* in_sizes, int n_in,
                              void* d_out, int out_size, void* d_ws, size_t ws_size,
                              hipStream_t stream) {
    (void)in_sizes; (void)n_in; (void)out_size; (void)ws_size;
    const float* f0 = (const float*)d_in[0];
    const float* f1 = (const float*)d_in[1];
    const float* f2 = (const float*)d_in[2];
    const float* f3 = (const float*)d_in[3];
    const float* Wq    = (const float*)d_in[4];
    const float* bq    = (const float*)d_in[5];
    const float* Wv    = (const float*)d_in[6];
    const float* bv    = (const float*)d_in[7];
    const float* Woff  = (const float*)d_in[8];
    const float* boff  = (const float*)d_in[9];
    const float* Wattn = (const float*)d_in[10];
    const float* battn = (const float*)d_in[11];
    const float* Wout  = (const float*)d_in[12];
    const float* bout  = (const float*)d_in[13];
    float* out = (float*)d_out;

    float* ws   = (float*)d_ws;
    float* XP   = ws;                       // 21760*256
    float* VAL  = XP  + (size_t)NR * 256;
    float* Q    = VAL + (size_t)NR * 256;
    float* OFFb = Q   + (size_t)NR * 256;
    float* ATT  = OFFb + (size_t)NR * 256;  // 21760*128
    float* SAMP = XP;                       // reuse XP after Q is built

    // K1: pack each level
    hipLaunchKernelGGL(pack_kernel, dim3(128, 4, 2), dim3(256), 0, stream, f0, XP, 64, 64, 0);
    hipLaunchKernelGGL(pack_kernel, dim3(32, 4, 2),  dim3(256), 0, stream, f1, XP, 32, 32, 16384);
    hipLaunchKernelGGL(pack_kernel, dim3(8, 4, 2),   dim3(256), 0, stream, f2, XP, 16, 16, 20480);
    hipLaunchKernelGGL(pack_kernel, dim3(2, 4, 2),   dim3(256), 0, stream, f3, XP, 8, 8, 21504);

    // K2: projections
    hipLaunchKernelGGL(gemm_kernel, dim3(NR / 64, 4), dim3(256), 0, stream, XP, Wv, bv, VAL, NR, 256, 256);
    hipLaunchKernelGGL(gemm_kernel, dim3(NR / 64, 4), dim3(256), 0, stream, XP, Wq, bq, Q,   NR, 256, 256);
    hipLaunchKernelGGL(gemm_kernel, dim3(NR / 64, 4), dim3(256), 0, stream, Q, Woff, boff, OFFb, NR, 256, 256);
    hipLaunchKernelGGL(gemm_kernel, dim3(NR / 64, 2), dim3(256), 0, stream, Q, Wattn, battn, ATT, NR, 128, 256);

    // K4: softmax over 16 per (row, head)
    hipLaunchKernelGGL(softmax_kernel, dim3((NR * 8 + 255) / 256), dim3(256), 0, stream, ATT);

    // K5: sampling
    hipLaunchKernelGGL(sample_kernel, dim3(NR / 8), dim3(256), 0, stream, VAL, OFFb, ATT, SAMP);

    // K6: output projection + scatter to [B,C,H,W,T] per level
    hipLaunchKernelGGL(gemm_scatter_kernel, dim3(NR / 64, 4), dim3(256), 0, stream, SAMP, Wout, bout, out, NR, 256);
}

// Round 2
// 257.939 us; speedup vs baseline: 2.1873x; 2.1873x over previous
//
#include <hip/hip_runtime.h>
#include <hip/hip_bf16.h>

// ---------------- problem constants ----------------------------------------
// B=2, T=2, C=256, heads=8, levels=4, points=4, head_dim=32
// level shapes: (64,64),(32,32),(16,16),(8,8); Bt=4
// rows per level (Bt*HW): 16384, 4096, 1024, 256 ; total NR=21760
#define NR 21760

typedef short short8 __attribute__((ext_vector_type(8)));
typedef float f32x4 __attribute__((ext_vector_type(4)));

__device__ __forceinline__ int level_of_row(int R) {
    if (R < 16384) return 0;
    if (R < 20480) return 1;
    if (R < 21504) return 2;
    return 3;
}

// ---------------- K1: pack [B,C,H,W,T] -> XPb[row][c] (bf16) ---------------
__global__ __launch_bounds__(256) void pack_kernel(const float* __restrict__ f,
                                                   __hip_bfloat16* __restrict__ XP,
                                                   int Hl, int Wl, int rowbase) {
    const int HW = Hl * Wl;
    const int HWT = HW * 2;
    const int j0 = blockIdx.x * 64;
    const int c0 = blockIdx.y * 64;
    const int b  = blockIdx.z;
    __shared__ float tile[64][65];
    {
        const int tj = threadIdx.x & 63;
        const int tcb = threadIdx.x >> 6;
        const float* fb = f + (size_t)(b * 256 + c0) * HWT + j0;
#pragma unroll
        for (int i = 0; i < 16; ++i) {
            int cl = tcb + i * 4;
            tile[cl][tj] = fb[(size_t)cl * HWT + tj];
        }
    }
    __syncthreads();
    {
        const int tc = threadIdx.x & 63;
        const int tjb = threadIdx.x >> 6;
#pragma unroll
        for (int i = 0; i < 16; ++i) {
            int jl = tjb + i * 4;
            int j = j0 + jl;
            int p = j >> 1, t = j & 1;
            int row = rowbase + (b * 2 + t) * HW + p;
            XP[(size_t)row * 256 + c0 + tc] = __float2bfloat16(tile[tc][jl]);
        }
    }
}

// ---------------- K2: weight transpose+convert  W[K][N] f32 -> WT[N][K] bf16
__global__ __launch_bounds__(256) void wtrans_kernel(const float* __restrict__ W,
                                                     __hip_bfloat16* __restrict__ WT,
                                                     int K, int N) {
    __shared__ float t[32][33];
    const int n0 = blockIdx.x * 32, k0 = blockIdx.y * 32;
    const int c = threadIdx.x & 31, r = threadIdx.x >> 5;  // r: 0..7
#pragma unroll
    for (int i = 0; i < 4; ++i)
        t[r + 8 * i][c] = W[(size_t)(k0 + r + 8 * i) * N + n0 + c];
    __syncthreads();
#pragma unroll
    for (int i = 0; i < 4; ++i)
        WT[(size_t)(n0 + r + 8 * i) * K + k0 + c] = __float2bfloat16(t[c][r + 8 * i]);
}

// ---------------- K3: bf16 MFMA GEMM  C = A[M,K] @ BT[N,K]^T + bias --------
// OUTMODE: 0 = f32, 1 = bf16, 2 = f32 scatter to [B,C,H,W,T] levels
template <int OUTMODE>
__global__ __launch_bounds__(256) void gemm_mfma(const __hip_bfloat16* __restrict__ A,
                                                 const __hip_bfloat16* __restrict__ BT,
                                                 const float* __restrict__ bias,
                                                 void* __restrict__ Cout,
                                                 int M, int N, int K) {
    __shared__ __align__(16) __hip_bfloat16 As[64][72];
    __shared__ __align__(16) __hip_bfloat16 Bs[64][72];
    const int m0 = blockIdx.x * 64;
    const int n0 = blockIdx.y * 64;
    const int w = threadIdx.x >> 6;
    const int lane = threadIdx.x & 63;
    const int wm = (w >> 1) * 32;
    const int wn = (w & 1) * 32;
    const int fr = lane & 15;   // frag row (A) / col (B/C)
    const int fq = lane >> 4;   // 0..3
    const int srow = threadIdx.x >> 3;    // 0..31
    const int schunk = threadIdx.x & 7;   // 0..7
    f32x4 acc[2][2] = {};

    for (int kt = 0; kt < K; kt += 64) {
        __syncthreads();
#pragma unroll
        for (int i = 0; i < 2; ++i) {
            int r = srow + 32 * i;
            float4 va = *(const float4*)(&A[(size_t)(m0 + r) * K + kt + schunk * 8]);
            *(float4*)(&As[r][schunk * 8]) = va;
            float4 vb = *(const float4*)(&BT[(size_t)(n0 + r) * K + kt + schunk * 8]);
            *(float4*)(&Bs[r][schunk * 8]) = vb;
        }
        __syncthreads();
#pragma unroll
        for (int ks = 0; ks < 2; ++ks) {
            short8 a[2], b[2];
#pragma unroll
            for (int fi = 0; fi < 2; ++fi)
                a[fi] = *(const short8*)(&As[wm + fi * 16 + fr][ks * 32 + fq * 8]);
#pragma unroll
            for (int fj = 0; fj < 2; ++fj)
                b[fj] = *(const short8*)(&Bs[wn + fj * 16 + fr][ks * 32 + fq * 8]);
#pragma unroll
            for (int fi = 0; fi < 2; ++fi)
#pragma unroll
                for (int fj = 0; fj < 2; ++fj)
                    acc[fi][fj] = __builtin_amdgcn_mfma_f32_16x16x32_bf16(
                        a[fi], b[fj], acc[fi][fj], 0, 0, 0);
        }
    }

    if (OUTMODE == 2) {
        const int lvl = level_of_row(m0);
        const int qbase[4]   = {0, 16384, 20480, 21504};
        const int wtab[4]    = {64, 32, 16, 8};
        const size_t obase[4] = {0, 4194304, 5242880, 5505024};
        const int Wl = wtab[lvl];
        const int HW = Wl * Wl;
        float* out = (float*)Cout;
#pragma unroll
        for (int fi = 0; fi < 2; ++fi)
#pragma unroll
            for (int fj = 0; fj < 2; ++fj) {
                int col = n0 + wn + fj * 16 + fr;
                float bb = bias[col];
#pragma unroll
                for (int r = 0; r < 4; ++r) {
                    int row = m0 + wm + fi * 16 + fq * 4 + r;
                    int r2 = row - qbase[lvl];
                    int bt = r2 / HW;
                    int p  = r2 - bt * HW;
                    int b  = bt >> 1, t = bt & 1;
                    int y  = p / Wl, x = p - y * Wl;
                    size_t addr = obase[lvl] +
                        ((((size_t)b * 256 + col) * Wl + y) * Wl + x) * 2 + t;
                    out[addr] = acc[fi][fj][r] + bb;
                }
            }
    } else {
#pragma unroll
        for (int fi = 0; fi < 2; ++fi)
#pragma unroll
            for (int fj = 0; fj < 2; ++fj) {
                int col = n0 + wn + fj * 16 + fr;
                float bb = bias[col];
#pragma unroll
                for (int r = 0; r < 4; ++r) {
                    int row = m0 + wm + fi * 16 + fq * 4 + r;
                    float v = acc[fi][fj][r] + bb;
                    if (OUTMODE == 0)
                        ((float*)Cout)[(size_t)row * N + col] = v;
                    else
                        ((__hip_bfloat16*)Cout)[(size_t)row * N + col] = __float2bfloat16(v);
                }
            }
    }
}

// ---------------- K4: softmax over 16 (L*K) per (row, head) ----------------
__global__ __launch_bounds__(256) void softmax_kernel(float* __restrict__ ATT) {
    int g = blockIdx.x * 256 + threadIdx.x;
    if (g >= NR * 8) return;
    float* p = ATT + (size_t)(g >> 3) * 128 + (g & 7) * 16;
    float v[16];
    float4* p4 = (float4*)p;
#pragma unroll
    for (int i = 0; i < 4; ++i) {
        float4 t = p4[i];
        v[i * 4 + 0] = t.x; v[i * 4 + 1] = t.y; v[i * 4 + 2] = t.z; v[i * 4 + 3] = t.w;
    }
    float m = v[0];
#pragma unroll
    for (int i = 1; i < 16; ++i) m = fmaxf(m, v[i]);
    float s = 0.f;
#pragma unroll
    for (int i = 0; i < 16; ++i) { v[i] = expf(v[i] - m); s += v[i]; }
    float r = 1.0f / s;
#pragma unroll
    for (int i = 0; i < 4; ++i) {
        float4 t;
        t.x = v[i * 4 + 0] * r; t.y = v[i * 4 + 1] * r; t.z = v[i * 4 + 2] * r; t.w = v[i * 4 + 3] * r;
        p4[i] = t;
    }
}

// ---------------- K5: sampling: LDS tap precompute + gather ----------------
struct __align__(16) Tap {
    int o00, o10, o01, o11;
    float w00, w10, w01, w11;
};

#define QB 4
__global__ __launch_bounds__(256) void sample_kernel(const float* __restrict__ VAL,
                                                     const float* __restrict__ OFF,
                                                     const float* __restrict__ AW,
                                                     __hip_bfloat16* __restrict__ SAMP) {
    __shared__ Tap taps[QB * 128];
    const int R0 = blockIdx.x * QB;
    const int tid = threadIdx.x;
    const int qbase[4] = {0, 16384, 20480, 21504};
    const int wtab[4]  = {64, 32, 16, 8};

    // phase 1: each thread precomputes QB*128/256 = 2 taps
#pragma unroll
    for (int it = 0; it < (QB * 128) / 256; ++it) {
        int g = it * 256 + tid;
        int qi = g >> 7;
        int hlk = g & 127;
        int h = hlk >> 4;
        int lk = hlk & 15;
        int l = lk >> 2;
        int R = R0 + qi;
        int lq = level_of_row(R);
        int Wq = wtab[lq];
        int HWq = Wq * Wq;
        int r2 = R - qbase[lq];
        int bt = r2 / HWq;
        int p  = r2 - bt * HWq;
        float refx = ((p % Wq) + 0.5f) / (float)Wq;
        float refy = ((p / Wq) + 0.5f) / (float)Wq;

        float ox = OFF[(size_t)R * 256 + h * 32 + lk * 2 + 0];
        float oy = OFF[(size_t)R * 256 + h * 32 + lk * 2 + 1];
        float aw = AW[(size_t)R * 128 + h * 16 + lk];
        int Wl = wtab[l];
        float invW = 1.0f / (float)Wl;
        float lx = fminf(fmaxf(refx + ox * invW, 0.f), 1.f);
        float ly = fminf(fmaxf(refy + oy * invW, 0.f), 1.f);
        float px = lx * Wl - 0.5f;
        float py = ly * Wl - 0.5f;
        float x0f = floorf(px), y0f = floorf(py);
        int x0 = (int)x0f, y0 = (int)y0f;
        float wx = px - x0f, wy = py - y0f;
        float vx0 = (x0 >= 0) ? 1.f : 0.f;
        float vx1 = (x0 + 1 <= Wl - 1) ? 1.f : 0.f;
        float vy0 = (y0 >= 0) ? 1.f : 0.f;
        float vy1 = (y0 + 1 <= Wl - 1) ? 1.f : 0.f;
        int x0c = max(x0, 0), x1c = min(x0 + 1, Wl - 1);
        int y0c = max(y0, 0), y1c = min(y0 + 1, Wl - 1);
        int base = (qbase[l] + bt * Wl * Wl) * 256;
        Tap tp;
        tp.o00 = base + (y0c * Wl + x0c) * 256;
        tp.o10 = base + (y0c * Wl + x1c) * 256;
        tp.o01 = base + (y1c * Wl + x0c) * 256;
        tp.o11 = base + (y1c * Wl + x1c) * 256;
        tp.w00 = aw * (1.f - wx) * (1.f - wy) * vx0 * vy0;
        tp.w10 = aw * wx * (1.f - wy) * vx1 * vy0;
        tp.w01 = aw * (1.f - wx) * wy * vx0 * vy1;
        tp.w11 = aw * wx * wy * vx1 * vy1;
        taps[qi * 128 + hlk] = tp;
    }
    __syncthreads();

    // phase 2: (h, d) lanes gather
    const int h = tid >> 5, d = tid & 31;
    const int hd = h * 32 + d;
#pragma unroll
    for (int qi = 0; qi < QB; ++qi) {
        float acc = 0.f;
        const Tap* tq = &taps[qi * 128 + h * 16];
#pragma unroll
        for (int t = 0; t < 16; ++t) {
            Tap tp = tq[t];
            acc += tp.w00 * VAL[tp.o00 + hd]
                 + tp.w10 * VAL[tp.o10 + hd]
                 + tp.w01 * VAL[tp.o01 + hd]
                 + tp.w11 * VAL[tp.o11 + hd];
        }
        SAMP[(size_t)(R0 + qi) * 256 + hd] = __float2bfloat16(acc);
    }
}

// ---------------- launch ---------------------------------------------------
extern "C" void kernel_launch(void* const* d_in, const int* in_sizes, int n_in,
                              void* d_out, int out_size, void* d_ws, size_t ws_size,
                              hipStream_t stream) {
    (void)in_sizes; (void)n_in; (void)out_size; (void)ws_size;
    const float* f0 = (const float*)d_in[0];
    const float* f1 = (const float*)d_in[1];
    const float* f2 = (const float*)d_in[2];
    const float* f3 = (const float*)d_in[3];
    const float* Wq    = (const float*)d_in[4];
    const float* bq    = (const float*)d_in[5];
    const float* Wv    = (const float*)d_in[6];
    const float* bv    = (const float*)d_in[7];
    const float* Woff  = (const float*)d_in[8];
    const float* boff  = (const float*)d_in[9];
    const float* Wattn = (const float*)d_in[10];
    const float* battn = (const float*)d_in[11];
    const float* Wout  = (const float*)d_in[12];
    const float* bout  = (const float*)d_in[13];
    float* out = (float*)d_out;

    char* w = (char*)d_ws;
    __hip_bfloat16* XPb   = (__hip_bfloat16*)w;                 w += (size_t)NR * 256 * 2;
    __hip_bfloat16* Qb    = (__hip_bfloat16*)w;                 w += (size_t)NR * 256 * 2;
    __hip_bfloat16* SAMPb = (__hip_bfloat16*)w;                 w += (size_t)NR * 256 * 2;
    float* VAL  = (float*)w;                                    w += (size_t)NR * 256 * 4;
    float* OFFb = (float*)w;                                    w += (size_t)NR * 256 * 4;
    float* ATT  = (float*)w;                                    w += (size_t)NR * 128 * 4;
    __hip_bfloat16* WTq   = (__hip_bfloat16*)w;                 w += 256 * 256 * 2;
    __hip_bfloat16* WTv   = (__hip_bfloat16*)w;                 w += 256 * 256 * 2;
    __hip_bfloat16* WToff = (__hip_bfloat16*)w;                 w += 256 * 256 * 2;
    __hip_bfloat16* WTattn= (__hip_bfloat16*)w;                 w += 128 * 256 * 2;
    __hip_bfloat16* WTout = (__hip_bfloat16*)w;                 w += 256 * 256 * 2;

    // K1: pack each level -> bf16 rows
    hipLaunchKernelGGL(pack_kernel, dim3(128, 4, 2), dim3(256), 0, stream, f0, XPb, 64, 64, 0);
    hipLaunchKernelGGL(pack_kernel, dim3(32, 4, 2),  dim3(256), 0, stream, f1, XPb, 32, 32, 16384);
    hipLaunchKernelGGL(pack_kernel, dim3(8, 4, 2),   dim3(256), 0, stream, f2, XPb, 16, 16, 20480);
    hipLaunchKernelGGL(pack_kernel, dim3(2, 4, 2),   dim3(256), 0, stream, f3, XPb, 8, 8, 21504);

    // K2: weight transposes (f32 -> bf16, [K][N] -> [N][K])
    hipLaunchKernelGGL(wtrans_kernel, dim3(8, 8), dim3(256), 0, stream, Wq,    WTq,    256, 256);
    hipLaunchKernelGGL(wtrans_kernel, dim3(8, 8), dim3(256), 0, stream, Wv,    WTv,    256, 256);
    hipLaunchKernelGGL(wtrans_kernel, dim3(8, 8), dim3(256), 0, stream, Woff,  WToff,  256, 256);
    hipLaunchKernelGGL(wtrans_kernel, dim3(4, 8), dim3(256), 0, stream, Wattn, WTattn, 256, 128);
    hipLaunchKernelGGL(wtrans_kernel, dim3(8, 8), dim3(256), 0, stream, Wout,  WTout,  256, 256);

    // K3: projections (MFMA)
    hipLaunchKernelGGL((gemm_mfma<0>), dim3(NR / 64, 4), dim3(256), 0, stream, XPb, WTv,    bv,    (void*)VAL,  NR, 256, 256);
    hipLaunchKernelGGL((gemm_mfma<1>), dim3(NR / 64, 4), dim3(256), 0, stream, XPb, WTq,    bq,    (void*)Qb,   NR, 256, 256);
    hipLaunchKernelGGL((gemm_mfma<0>), dim3(NR / 64, 4), dim3(256), 0, stream, Qb,  WToff,  boff,  (void*)OFFb, NR, 256, 256);
    hipLaunchKernelGGL((gemm_mfma<0>), dim3(NR / 64, 2), dim3(256), 0, stream, Qb,  WTattn, battn, (void*)ATT,  NR, 128, 256);

    // K4: softmax over 16 per (row, head)
    hipLaunchKernelGGL(softmax_kernel, dim3((NR * 8 + 255) / 256), dim3(256), 0, stream, ATT);

    // K5: sampling
    hipLaunchKernelGGL(sample_kernel, dim3(NR / QB), dim3(256), 0, stream, VAL, OFFb, ATT, SAMPb);

    // K6: output projection + scatter
    hipLaunchKernelGGL((gemm_mfma<2>), dim3(NR / 64, 4), dim3(256), 0, stream, SAMPb, WTout, bout, (void*)out, NR, 256, 256);
}

// Round 3
// 150.674 us; speedup vs baseline: 3.7444x; 1.7119x over previous
//
#include <hip/hip_runtime.h>
#include <hip/hip_bf16.h>

// ---------------- problem constants ----------------------------------------
// B=2, T=2, C=256, heads=8, levels=4, points=4, head_dim=32
// level shapes: (64,64),(32,32),(16,16),(8,8); Bt=4
// rows per level (Bt*HW): 16384, 4096, 1024, 256 ; total NR=21760
#define NR 21760

typedef short short8 __attribute__((ext_vector_type(8)));
typedef float f32x4 __attribute__((ext_vector_type(4)));

__device__ __forceinline__ int level_of_row(int R) {
    if (R < 16384) return 0;
    if (R < 20480) return 1;
    if (R < 21504) return 2;
    return 3;
}

// ---------------- K1: pack [B,C,H,W,T] -> XPb[row][c] (bf16) ---------------
__global__ __launch_bounds__(256) void pack_kernel(const float* __restrict__ f,
                                                   __hip_bfloat16* __restrict__ XP,
                                                   int Hl, int Wl, int rowbase) {
    const int HW = Hl * Wl;
    const int HWT = HW * 2;
    const int j0 = blockIdx.x * 64;
    const int c0 = blockIdx.y * 64;
    const int b  = blockIdx.z;
    __shared__ float tile[64][65];
    {
        const int tj = threadIdx.x & 63;
        const int tcb = threadIdx.x >> 6;
        const float* fb = f + (size_t)(b * 256 + c0) * HWT + j0;
#pragma unroll
        for (int i = 0; i < 16; ++i) {
            int cl = tcb + i * 4;
            tile[cl][tj] = fb[(size_t)cl * HWT + tj];
        }
    }
    __syncthreads();
    {
        const int tc = threadIdx.x & 63;
        const int tjb = threadIdx.x >> 6;
#pragma unroll
        for (int i = 0; i < 16; ++i) {
            int jl = tjb + i * 4;
            int j = j0 + jl;
            int p = j >> 1, t = j & 1;
            int row = rowbase + (b * 2 + t) * HW + p;
            XP[(size_t)row * 256 + c0 + tc] = __float2bfloat16(tile[tc][jl]);
        }
    }
}

// ---------------- K2: weight transpose+convert  W[K][N] f32 -> WT[N][K] bf16
__global__ __launch_bounds__(256) void wtrans_kernel(const float* __restrict__ W,
                                                     __hip_bfloat16* __restrict__ WT,
                                                     int K, int N) {
    __shared__ float t[32][33];
    const int n0 = blockIdx.x * 32, k0 = blockIdx.y * 32;
    const int c = threadIdx.x & 31, r = threadIdx.x >> 5;  // r: 0..7
#pragma unroll
    for (int i = 0; i < 4; ++i)
        t[r + 8 * i][c] = W[(size_t)(k0 + r + 8 * i) * N + n0 + c];
    __syncthreads();
#pragma unroll
    for (int i = 0; i < 4; ++i)
        WT[(size_t)(n0 + r + 8 * i) * K + k0 + c] = __float2bfloat16(t[c][r + 8 * i]);
}

// ---------------- K3: bf16 MFMA GEMM  C = A[M,K] @ BT[N,K]^T + bias --------
// OUTMODE: 0 = f32, 1 = bf16, 2 = f32 scatter to [B,C,H,W,T] levels
template <int OUTMODE>
__global__ __launch_bounds__(256) void gemm_mfma(const __hip_bfloat16* __restrict__ A,
                                                 const __hip_bfloat16* __restrict__ BT,
                                                 const float* __restrict__ bias,
                                                 void* __restrict__ Cout,
                                                 int M, int N, int K) {
    __shared__ __align__(16) __hip_bfloat16 As[64][72];
    __shared__ __align__(16) __hip_bfloat16 Bs[64][72];
    const int m0 = blockIdx.x * 64;
    const int n0 = blockIdx.y * 64;
    const int w = threadIdx.x >> 6;
    const int lane = threadIdx.x & 63;
    const int wm = (w >> 1) * 32;
    const int wn = (w & 1) * 32;
    const int fr = lane & 15;   // frag row (A) / col (B/C)
    const int fq = lane >> 4;   // 0..3
    const int srow = threadIdx.x >> 3;    // 0..31
    const int schunk = threadIdx.x & 7;   // 0..7
    f32x4 acc[2][2] = {};

    for (int kt = 0; kt < K; kt += 64) {
        __syncthreads();
#pragma unroll
        for (int i = 0; i < 2; ++i) {
            int r = srow + 32 * i;
            float4 va = *(const float4*)(&A[(size_t)(m0 + r) * K + kt + schunk * 8]);
            *(float4*)(&As[r][schunk * 8]) = va;
            float4 vb = *(const float4*)(&BT[(size_t)(n0 + r) * K + kt + schunk * 8]);
            *(float4*)(&Bs[r][schunk * 8]) = vb;
        }
        __syncthreads();
#pragma unroll
        for (int ks = 0; ks < 2; ++ks) {
            short8 a[2], b[2];
#pragma unroll
            for (int fi = 0; fi < 2; ++fi)
                a[fi] = *(const short8*)(&As[wm + fi * 16 + fr][ks * 32 + fq * 8]);
#pragma unroll
            for (int fj = 0; fj < 2; ++fj)
                b[fj] = *(const short8*)(&Bs[wn + fj * 16 + fr][ks * 32 + fq * 8]);
#pragma unroll
            for (int fi = 0; fi < 2; ++fi)
#pragma unroll
                for (int fj = 0; fj < 2; ++fj)
                    acc[fi][fj] = __builtin_amdgcn_mfma_f32_16x16x32_bf16(
                        a[fi], b[fj], acc[fi][fj], 0, 0, 0);
        }
    }

    if (OUTMODE == 2) {
        const int lvl = level_of_row(m0);
        const int qbase[4]   = {0, 16384, 20480, 21504};
        const int wtab[4]    = {64, 32, 16, 8};
        const size_t obase[4] = {0, 4194304, 5242880, 5505024};
        const int Wl = wtab[lvl];
        const int HW = Wl * Wl;
        float* out = (float*)Cout;
#pragma unroll
        for (int fi = 0; fi < 2; ++fi)
#pragma unroll
            for (int fj = 0; fj < 2; ++fj) {
                int col = n0 + wn + fj * 16 + fr;
                float bb = bias[col];
#pragma unroll
                for (int r = 0; r < 4; ++r) {
                    int row = m0 + wm + fi * 16 + fq * 4 + r;
                    int r2 = row - qbase[lvl];
                    int bt = r2 / HW;
                    int p  = r2 - bt * HW;
                    int b  = bt >> 1, t = bt & 1;
                    int y  = p / Wl, x = p - y * Wl;
                    size_t addr = obase[lvl] +
                        ((((size_t)b * 256 + col) * Wl + y) * Wl + x) * 2 + t;
                    out[addr] = acc[fi][fj][r] + bb;
                }
            }
    } else {
#pragma unroll
        for (int fi = 0; fi < 2; ++fi)
#pragma unroll
            for (int fj = 0; fj < 2; ++fj) {
                int col = n0 + wn + fj * 16 + fr;
                float bb = bias[col];
#pragma unroll
                for (int r = 0; r < 4; ++r) {
                    int row = m0 + wm + fi * 16 + fq * 4 + r;
                    float v = acc[fi][fj][r] + bb;
                    if (OUTMODE == 0)
                        ((float*)Cout)[(size_t)row * N + col] = v;
                    else
                        ((__hip_bfloat16*)Cout)[(size_t)row * N + col] = __float2bfloat16(v);
                }
            }
    }
}

// ---------------- K4: softmax over 16 per (row, head); cols 256..383 of OA -
__global__ __launch_bounds__(256) void softmax_kernel(float* __restrict__ OA) {
    int g = blockIdx.x * 256 + threadIdx.x;
    if (g >= NR * 8) return;
    float* p = OA + (size_t)(g >> 3) * 384 + 256 + (g & 7) * 16;
    float v[16];
    float4* p4 = (float4*)p;
#pragma unroll
    for (int i = 0; i < 4; ++i) {
        float4 t = p4[i];
        v[i * 4 + 0] = t.x; v[i * 4 + 1] = t.y; v[i * 4 + 2] = t.z; v[i * 4 + 3] = t.w;
    }
    float m = v[0];
#pragma unroll
    for (int i = 1; i < 16; ++i) m = fmaxf(m, v[i]);
    float s = 0.f;
#pragma unroll
    for (int i = 0; i < 16; ++i) { v[i] = expf(v[i] - m); s += v[i]; }
    float r = 1.0f / s;
#pragma unroll
    for (int i = 0; i < 4; ++i) {
        float4 t;
        t.x = v[i * 4 + 0] * r; t.y = v[i * 4 + 1] * r; t.z = v[i * 4 + 2] * r; t.w = v[i * 4 + 3] * r;
        p4[i] = t;
    }
}

// ---------------- K5: sampling: LDS tap precompute + float4 gather ---------
struct __align__(16) Tap {
    int o00, o10, o01, o11;
    float w00, w10, w01, w11;
};

#define QB 4
__global__ __launch_bounds__(256, 2) void sample_kernel(const float* __restrict__ VAL,
                                                        const float* __restrict__ OA,
                                                        __hip_bfloat16* __restrict__ SAMP) {
    __shared__ Tap taps[QB * 128];   // [q][t(16)][h(8)]
    const int R0 = blockIdx.x * QB;
    const int tid = threadIdx.x;
    const int qbase[4] = {0, 16384, 20480, 21504};
    const int wtab[4]  = {64, 32, 16, 8};

    // phase 1: 512 taps per block, 2 per thread
#pragma unroll
    for (int it = 0; it < (QB * 128) / 256; ++it) {
        int g = it * 256 + tid;
        int qi = g >> 7;
        int h  = g & 7;
        int lk = (g >> 3) & 15;
        int l  = lk >> 2;
        int R = R0 + qi;
        int lq = level_of_row(R);
        int Wq = wtab[lq];
        int HWq = Wq * Wq;
        int r2 = R - qbase[lq];
        int bt = r2 / HWq;
        int p  = r2 - bt * HWq;
        float refx = ((p % Wq) + 0.5f) / (float)Wq;
        float refy = ((p / Wq) + 0.5f) / (float)Wq;

        float ox = OA[(size_t)R * 384 + h * 32 + lk * 2 + 0];
        float oy = OA[(size_t)R * 384 + h * 32 + lk * 2 + 1];
        float aw = OA[(size_t)R * 384 + 256 + h * 16 + lk];
        int Wl = wtab[l];
        float invW = 1.0f / (float)Wl;
        float lx = fminf(fmaxf(refx + ox * invW, 0.f), 1.f);
        float ly = fminf(fmaxf(refy + oy * invW, 0.f), 1.f);
        float px = lx * Wl - 0.5f;
        float py = ly * Wl - 0.5f;
        float x0f = floorf(px), y0f = floorf(py);
        int x0 = (int)x0f, y0 = (int)y0f;
        float wx = px - x0f, wy = py - y0f;
        float vx0 = (x0 >= 0) ? 1.f : 0.f;
        float vx1 = (x0 + 1 <= Wl - 1) ? 1.f : 0.f;
        float vy0 = (y0 >= 0) ? 1.f : 0.f;
        float vy1 = (y0 + 1 <= Wl - 1) ? 1.f : 0.f;
        int x0c = max(x0, 0), x1c = min(x0 + 1, Wl - 1);
        int y0c = max(y0, 0), y1c = min(y0 + 1, Wl - 1);
        int base = (qbase[l] + bt * Wl * Wl) * 256;
        Tap tp;
        tp.o00 = base + (y0c * Wl + x0c) * 256;
        tp.o10 = base + (y0c * Wl + x1c) * 256;
        tp.o01 = base + (y1c * Wl + x0c) * 256;
        tp.o11 = base + (y1c * Wl + x1c) * 256;
        tp.w00 = aw * (1.f - wx) * (1.f - wy) * vx0 * vy0;
        tp.w10 = aw * wx * (1.f - wy) * vx1 * vy0;
        tp.w01 = aw * (1.f - wx) * wy * vx0 * vy1;
        tp.w11 = aw * wx * wy * vx1 * vy1;
        taps[qi * 128 + lk * 8 + h] = tp;
    }
    __syncthreads();

    // phase 2: one wave per query; lane = (head, d4); float4 per lane
    const int wq = tid >> 6;
    const int lane = tid & 63;
    const int h = lane >> 3;
    const int d4 = lane & 7;
    const int R = R0 + wq;
    const float* vbase = VAL + h * 32 + d4 * 4;
    const Tap* tq = &taps[wq * 128];
    f32x4 acc = {0.f, 0.f, 0.f, 0.f};
#pragma unroll
    for (int t = 0; t < 16; ++t) {
        Tap tp = tq[t * 8 + h];
        f32x4 v00 = *(const f32x4*)(vbase + tp.o00);
        f32x4 v10 = *(const f32x4*)(vbase + tp.o10);
        f32x4 v01 = *(const f32x4*)(vbase + tp.o01);
        f32x4 v11 = *(const f32x4*)(vbase + tp.o11);
        acc += tp.w00 * v00 + tp.w10 * v10 + tp.w01 * v01 + tp.w11 * v11;
    }
    union { ushort u[4]; ushort2 v2[2]; } s;
#pragma unroll
    for (int i = 0; i < 4; ++i) {
        __hip_bfloat16 b = __float2bfloat16(acc[i]);
        s.u[i] = *(ushort*)&b;
    }
    *(ushort2*)(&SAMP[(size_t)R * 256 + h * 32 + d4 * 4]) = s.v2[0];
    *(ushort2*)(&SAMP[(size_t)R * 256 + h * 32 + d4 * 4 + 2]) = s.v2[1];
}

// ---------------- launch ---------------------------------------------------
extern "C" void kernel_launch(void* const* d_in, const int* in_sizes, int n_in,
                              void* d_out, int out_size, void* d_ws, size_t ws_size,
                              hipStream_t stream) {
    (void)in_sizes; (void)n_in; (void)out_size; (void)ws_size;
    const float* f0 = (const float*)d_in[0];
    const float* f1 = (const float*)d_in[1];
    const float* f2 = (const float*)d_in[2];
    const float* f3 = (const float*)d_in[3];
    const float* Wq    = (const float*)d_in[4];
    const float* bq    = (const float*)d_in[5];
    const float* Wv    = (const float*)d_in[6];
    const float* bv    = (const float*)d_in[7];
    const float* Woff  = (const float*)d_in[8];
    const float* boff  = (const float*)d_in[9];
    const float* Wattn = (const float*)d_in[10];
    const float* battn = (const float*)d_in[11];
    const float* Wout  = (const float*)d_in[12];
    const float* bout  = (const float*)d_in[13];
    float* out = (float*)d_out;

    char* w = (char*)d_ws;
    __hip_bfloat16* XPb   = (__hip_bfloat16*)w;   w += (size_t)NR * 256 * 2;
    __hip_bfloat16* Qb    = (__hip_bfloat16*)w;   w += (size_t)NR * 256 * 2;
    __hip_bfloat16* SAMPb = (__hip_bfloat16*)w;   w += (size_t)NR * 256 * 2;
    float* VAL  = (float*)w;                      w += (size_t)NR * 256 * 4;
    float* OA   = (float*)w;                      w += (size_t)NR * 384 * 4;   // [OFF(256)|ATT(128)]
    __hip_bfloat16* WTq   = (__hip_bfloat16*)w;   w += 256 * 256 * 2;
    __hip_bfloat16* WTv   = (__hip_bfloat16*)w;   w += 256 * 256 * 2;
    __hip_bfloat16* WToa  = (__hip_bfloat16*)w;   w += 384 * 256 * 2;          // [WToff(256)|WTattn(128)] rows
    __hip_bfloat16* WTout = (__hip_bfloat16*)w;   w += 256 * 256 * 2;
    float* bias_oa = (float*)w;                   w += 384 * 4;

    // K1: pack each level -> bf16 rows
    hipLaunchKernelGGL(pack_kernel, dim3(128, 4, 2), dim3(256), 0, stream, f0, XPb, 64, 64, 0);
    hipLaunchKernelGGL(pack_kernel, dim3(32, 4, 2),  dim3(256), 0, stream, f1, XPb, 32, 32, 16384);
    hipLaunchKernelGGL(pack_kernel, dim3(8, 4, 2),   dim3(256), 0, stream, f2, XPb, 16, 16, 20480);
    hipLaunchKernelGGL(pack_kernel, dim3(2, 4, 2),   dim3(256), 0, stream, f3, XPb, 8, 8, 21504);

    // K2: weight transposes (f32 -> bf16, [K][N] -> [N][K]); OFF+ATT concatenated
    hipLaunchKernelGGL(wtrans_kernel, dim3(8, 8), dim3(256), 0, stream, Wq,    WTq,          256, 256);
    hipLaunchKernelGGL(wtrans_kernel, dim3(8, 8), dim3(256), 0, stream, Wv,    WTv,          256, 256);
    hipLaunchKernelGGL(wtrans_kernel, dim3(8, 8), dim3(256), 0, stream, Woff,  WToa,         256, 256);
    hipLaunchKernelGGL(wtrans_kernel, dim3(4, 8), dim3(256), 0, stream, Wattn, WToa + 256 * 256, 256, 128);
    hipLaunchKernelGGL(wtrans_kernel, dim3(8, 8), dim3(256), 0, stream, Wout,  WTout,        256, 256);
    hipMemcpyAsync(bias_oa,       boff,  256 * sizeof(float), hipMemcpyDeviceToDevice, stream);
    hipMemcpyAsync(bias_oa + 256, battn, 128 * sizeof(float), hipMemcpyDeviceToDevice, stream);

    // K3: projections (MFMA)
    hipLaunchKernelGGL((gemm_mfma<0>), dim3(NR / 64, 4), dim3(256), 0, stream, XPb, WTv,  bv,      (void*)VAL, NR, 256, 256);
    hipLaunchKernelGGL((gemm_mfma<1>), dim3(NR / 64, 4), dim3(256), 0, stream, XPb, WTq,  bq,      (void*)Qb,  NR, 256, 256);
    hipLaunchKernelGGL((gemm_mfma<0>), dim3(NR / 64, 6), dim3(256), 0, stream, Qb,  WToa, bias_oa, (void*)OA,  NR, 384, 256);

    // K4: softmax over 16 per (row, head) on ATT columns of OA
    hipLaunchKernelGGL(softmax_kernel, dim3((NR * 8 + 255) / 256), dim3(256), 0, stream, OA);

    // K5: sampling
    hipLaunchKernelGGL(sample_kernel, dim3(NR / QB), dim3(256), 0, stream, VAL, OA, SAMPb);

    // K6: output projection + scatter
    hipLaunchKernelGGL((gemm_mfma<2>), dim3(NR / 64, 4), dim3(256), 0, stream, SAMPb, WTout, bout, (void*)out, NR, 256, 256);
}